// Round 2
// baseline (12568.624 us; speedup 1.0000x reference)
//
#include <hip/hip_runtime.h>
#include <math.h>

#define HID 512
#define SEQ 512
#define EMB 345
#define NN  513
#define MPAD 576
#define H4  2048
#define H2  1024

// ---------------------------------------------------------------- GEMM (NT)
// C[m][n] = sum_k A[m][k]*B[n][k] (+ bias[n]); BM=BN=64, TK=16, 256 thr, 4x4
__global__ __launch_bounds__(256)
void gemm_nt(const float* __restrict__ A, int lda, long aStride,
             const float* __restrict__ B, int ldb, long bStride,
             const float* __restrict__ bias, long biasStride,
             float* __restrict__ C, int ldc, long cStride, int K)
{
    int z = blockIdx.z;
    A += (long)z * aStride; B += (long)z * bStride; C += (long)z * cStride;
    const float* bptr = bias ? bias + (long)z * biasStride : nullptr;
    __shared__ float As[16][68];
    __shared__ float Bs[16][68];
    int tid = threadIdx.x;
    int tx = tid & 15, ty = tid >> 4;
    int m0 = blockIdx.y * 64, n0 = blockIdx.x * 64;
    float acc[4][4] = {};
    for (int k0 = 0; k0 < K; k0 += 16) {
        #pragma unroll
        for (int i = 0; i < 4; i++) {
            int id = tid + 256 * i;
            int mn = id >> 4, kk = id & 15;
            int k = k0 + kk;
            As[kk][mn] = (k < K) ? A[(long)(m0 + mn) * lda + k] : 0.f;
            Bs[kk][mn] = (k < K) ? B[(long)(n0 + mn) * ldb + k] : 0.f;
        }
        __syncthreads();
        #pragma unroll
        for (int kk = 0; kk < 16; kk++) {
            float a[4], b[4];
            #pragma unroll
            for (int i = 0; i < 4; i++) a[i] = As[kk][ty * 4 + i];
            #pragma unroll
            for (int j = 0; j < 4; j++) b[j] = Bs[kk][tx * 4 + j];
            #pragma unroll
            for (int i = 0; i < 4; i++)
                #pragma unroll
                for (int j = 0; j < 4; j++) acc[i][j] += a[i] * b[j];
        }
        __syncthreads();
    }
    #pragma unroll
    for (int i = 0; i < 4; i++) {
        int m = m0 + ty * 4 + i;
        #pragma unroll
        for (int j = 0; j < 4; j++) {
            int n = n0 + tx * 4 + j;
            float v = acc[i][j];
            if (bptr) v += bptr[n];
            C[(long)m * ldc + n] = v;
        }
    }
}

// ---------------------------------------------------------------- LSTM layer
__device__ __forceinline__ float sigmf(float x) { return 1.f / (1.f + __expf(-x)); }

// 64 WGs: wg>>5 = dir, (wg&31)*16 = cell base. Weights register-resident.
// Per-WG flags on separate 128B cachelines (no atomic RMW). Producer:
// h stores (relaxed,agent) then flag release-store by tid0 (same wave ->
// vmcnt(0) drains exactly the h stores). Consumers: 32 relaxed pollers +
// one __threadfence() after all flags observed.
__global__ __launch_bounds__(256, 1)
void lstm_layer(const float* __restrict__ zin,   // [2][SEQ][H4]
                const float* __restrict__ Whh,   // [2][H4][HID]
                float* __restrict__ out,         // [SEQ][H2]
                float* hbuf,                     // [2][2][HID] double buffer
                int* flags)                      // [2][32][32] (128B stride)
{
    int wg  = blockIdx.x;
    int dir = wg >> 5;
    int wid = wg & 31;
    int kb  = wid * 16;
    int tid = threadIdx.x;
    int r = tid >> 2;          // row (gate*16 + kq), 0..63; wave w = gate w
    int p = tid & 3;           // k-part 0..3 (lane-adjacent for one row)
    int gate = r >> 4;
    int kq = r & 15;
    long row = (long)gate * 512 + kb + kq;

    __shared__ float h_lds[512];
    __shared__ float rowsum[64];

    float4 wreg[32];
    const float4* wp = (const float4*)(Whh + ((long)dir * H4 + row) * HID + p * 128);
    #pragma unroll
    for (int j = 0; j < 32; j++) wreg[j] = wp[j];

    const float* zin_d = zin + (long)dir * SEQ * H4;
    float* hb = hbuf + dir * 2 * HID;
    int* myflag   = flags + (dir * 32 + wid) * 32;
    int* pollflag = flags + (dir * 32 + (tid & 31)) * 32;
    float c_st = 0.f;

    for (int t = 0; t < SEQ; t++) {
        int at = (dir == 0) ? t : (SEQ - 1 - t);
        // prefetch zin (independent of the wait)
        float z0 = 0.f, z1 = 0.f, z2 = 0.f, z3 = 0.f;
        if (tid < 16) {
            const float* zp = zin_d + (long)at * H4 + kb + tid;
            z0 = zp[0]; z1 = zp[512]; z2 = zp[1024]; z3 = zp[1536];
        }
        if (t == 0) {
            h_lds[tid] = 0.f; h_lds[tid + 256] = 0.f;
        } else {
            if (tid < 32) {
                while (__hip_atomic_load(pollflag, __ATOMIC_RELAXED, __HIP_MEMORY_SCOPE_AGENT) < t)
                    __builtin_amdgcn_s_sleep(1);
            }
            __threadfence();
            __syncthreads();   // barrier A: all flags seen; h_lds from step t-1 free
            const float* hsrc = hb + (((t - 1) & 1) ? HID : 0);
            h_lds[tid]       = __hip_atomic_load(hsrc + tid,       __ATOMIC_RELAXED, __HIP_MEMORY_SCOPE_AGENT);
            h_lds[tid + 256] = __hip_atomic_load(hsrc + tid + 256, __ATOMIC_RELAXED, __HIP_MEMORY_SCOPE_AGENT);
        }
        __syncthreads();       // barrier B: h_lds ready
        const float4* h4 = (const float4*)(h_lds + p * 128);
        float4 av = {0.f, 0.f, 0.f, 0.f};
        #pragma unroll
        for (int j = 0; j < 32; j++) {
            float4 w = wreg[j], h = h4[j];
            av.x += w.x * h.x; av.y += w.y * h.y;
            av.z += w.z * h.z; av.w += w.w * h.w;
        }
        float partial = (av.x + av.y) + (av.z + av.w);
        partial += __shfl_xor(partial, 1);
        partial += __shfl_xor(partial, 2);
        if ((tid & 3) == 0) rowsum[r] = partial;
        __syncthreads();       // barrier C: rowsum ready (also fences h_lds reads)
        float hh = 0.f;
        if (tid < 16) {
            float zi = z0 + rowsum[tid];
            float zf = z1 + rowsum[16 + tid];
            float zg = z2 + rowsum[32 + tid];
            float zo = z3 + rowsum[48 + tid];
            float cc = sigmf(zf) * c_st + sigmf(zi) * tanhf(zg);
            c_st = cc;
            hh = sigmf(zo) * tanhf(cc);
            // publish h FIRST (only these stores gate the release drain)
            __hip_atomic_store(hb + ((t & 1) ? HID : 0) + kb + tid, hh,
                               __ATOMIC_RELAXED, __HIP_MEMORY_SCOPE_AGENT);
        }
        if (tid == 0)
            __hip_atomic_store(myflag, t + 1, __ATOMIC_RELEASE, __HIP_MEMORY_SCOPE_AGENT);
        if (tid < 16)
            out[(long)at * H2 + dir * HID + kb + tid] = hh;
    }
}

// ---------------------------------------------------------------- avail build
__global__ __launch_bounds__(256)
void build_avail(const float* __restrict__ lstm_out, float* __restrict__ avail)
{
    long idx = (long)blockIdx.x * 256 + threadIdx.x;   // over MPAD*H2
    if (idx >= (long)MPAD * H2) return;
    int i = (int)(idx >> 10);
    int c = (int)(idx & 1023);
    float v = 0.f;
    if (i >= 1 && i <= SEQ) v = lstm_out[(long)(i - 1) * H2 + c];
    avail[idx] = v;
}

// ---------------------------------------------------------------- transpose
__global__ __launch_bounds__(256)
void transpose_w(const float* __restrict__ W, float* __restrict__ WT, int rows, int cols)
{
    int idx = blockIdx.x * 256 + threadIdx.x;
    if (idx >= rows * cols) return;
    int rr = idx / cols, cc = idx % cols;
    WT[cc * rows + rr] = W[idx];
}

// ---------------------------------------------------------------- pair MLP
#define STR1 257
#define STR2 129
__global__ __launch_bounds__(256)
void pair_kernel(const float* __restrict__ Abuf, const float* __restrict__ Bbuf,
                 const float* __restrict__ b1, const float* __restrict__ W2T,
                 const float* __restrict__ b2, const float* __restrict__ W3T,
                 const float* __restrict__ b3, const float* __restrict__ W4,
                 const float* __restrict__ b4, float* __restrict__ S)
{
    __shared__ float At[8 * STR1];
    __shared__ float Bt[8 * STR1];
    __shared__ float b1s[256];
    __shared__ float h2s[64 * STR2];
    __shared__ float spart[4 * 64];
    int tid = threadIdx.x;
    int i0 = blockIdx.y * 8, j0 = blockIdx.x * 8;
    {
        int rr = tid >> 5;
        int cbase = (tid & 31) * 8;
        #pragma unroll
        for (int u = 0; u < 8; u++) {
            At[rr * STR1 + cbase + u] = Abuf[(long)(i0 + rr) * 256 + cbase + u];
            Bt[rr * STR1 + cbase + u] = Bbuf[(long)(j0 + rr) * 256 + cbase + u];
        }
        b1s[tid] = b1[tid];
    }
    __syncthreads();
    int w = tid >> 6;
    int lane = tid & 63;          // pair id
    int ii = lane >> 3, jj = lane & 7;
    // phase 2: h1 (on the fly) -> h2
    #pragma unroll 1
    for (int blk = 0; blk < 4; blk++) {
        int c2b = __builtin_amdgcn_readfirstlane(w * 32 + blk * 8);
        float acc[8] = {};
        #pragma unroll 4
        for (int c1 = 0; c1 < 256; c1++) {
            float h1v = At[ii * STR1 + c1] + Bt[jj * STR1 + c1] + b1s[c1];
            h1v = fmaxf(h1v, 0.f);
            const float* wrow = W2T + c1 * 128 + c2b;
            #pragma unroll
            for (int u = 0; u < 8; u++) acc[u] += wrow[u] * h1v;
        }
        #pragma unroll
        for (int u = 0; u < 8; u++)
            h2s[lane * STR2 + c2b + u] = fmaxf(acc[u] + b2[c2b + u], 0.f);
    }
    __syncthreads();
    // phase 3: h2 -> h3, W4 fused
    float sp = 0.f;
    #pragma unroll 1
    for (int blk = 0; blk < 2; blk++) {
        int c3b = __builtin_amdgcn_readfirstlane(w * 16 + blk * 8);
        float acc[8] = {};
        #pragma unroll 4
        for (int c2 = 0; c2 < 128; c2++) {
            float h2v = h2s[lane * STR2 + c2];
            const float* wrow = W3T + c2 * 64 + c3b;
            #pragma unroll
            for (int u = 0; u < 8; u++) acc[u] += wrow[u] * h2v;
        }
        #pragma unroll
        for (int u = 0; u < 8; u++) {
            float v = fmaxf(acc[u] + b3[c3b + u], 0.f);
            sp += W4[c3b + u] * v;
        }
    }
    spart[w * 64 + lane] = sp;
    __syncthreads();
    if (tid < 64) {
        float s = spart[tid] + spart[64 + tid] + spart[128 + tid] + spart[192 + tid] + b4[0];
        int i = i0 + (tid >> 3), j = j0 + (tid & 7);
        if (i < NN && j < NN) S[(long)i * NN + j] = s;
    }
}

// ---------------------------------------------------------------- softmax+loss
__global__ __launch_bounds__(256)
void softmax_row(const float* __restrict__ S, const int* __restrict__ heads,
                 float* __restrict__ probs, float* __restrict__ rowloss)
{
    int i = blockIdx.x;
    int tid = threadIdx.x;
    __shared__ float red[256];
    __shared__ float srow[NN];
    const float* Si = S + (long)i * NN;
    float mx = -1e30f;
    for (int j = tid; j < NN; j += 256) { float v = Si[j]; srow[j] = v; mx = fmaxf(mx, v); }
    red[tid] = mx; __syncthreads();
    for (int s = 128; s > 0; s >>= 1) { if (tid < s) red[tid] = fmaxf(red[tid], red[tid + s]); __syncthreads(); }
    mx = red[0]; __syncthreads();
    float sum = 0.f, sq = 0.f;
    int hd = heads[i];
    for (int j = tid; j < NN; j += 256) {
        float v = srow[j];
        sum += __expf(v - mx);
        float t = (j == hd) ? 100.f : 0.f;
        float d = v - t; sq += d * d;
    }
    red[tid] = sum; __syncthreads();
    for (int s = 128; s > 0; s >>= 1) { if (tid < s) red[tid] += red[tid + s]; __syncthreads(); }
    sum = red[0]; __syncthreads();
    red[tid] = sq; __syncthreads();
    for (int s = 128; s > 0; s >>= 1) { if (tid < s) red[tid] += red[tid + s]; __syncthreads(); }
    if (tid == 0) rowloss[i] = red[0];
    float inv = 1.f / sum;
    for (int j = tid; j < NN; j += 256) probs[(long)i * NN + j] = __expf(srow[j] - mx) * inv;
}

__global__ __launch_bounds__(256)
void finish_loss(const float* __restrict__ rowloss, float* __restrict__ out0)
{
    __shared__ float red[256];
    int tid = threadIdx.x;
    float s = 0.f;
    for (int i = tid; i < NN; i += 256) s += rowloss[i];
    red[tid] = s; __syncthreads();
    for (int k = 128; k > 0; k >>= 1) { if (tid < k) red[tid] += red[tid + k]; __syncthreads(); }
    if (tid == 0) out0[0] = red[0] / ((float)NN * (float)NN);
}

// ---------------------------------------------------------------- launch
extern "C" void kernel_launch(void* const* d_in, const int* in_sizes, int n_in,
                              void* d_out, int out_size, void* d_ws, size_t ws_size,
                              hipStream_t stream)
{
    const float* x     = (const float*)d_in[0];
    const int*   heads = (const int*)  d_in[1];
    const float* Wih0  = (const float*)d_in[2];
    const float* Whh0  = (const float*)d_in[3];
    const float* b0    = (const float*)d_in[4];
    const float* Wih_r = (const float*)d_in[5];
    const float* Whh_r = (const float*)d_in[6];
    const float* b_r   = (const float*)d_in[7];
    const float* W1    = (const float*)d_in[8];
    const float* b1    = (const float*)d_in[9];
    const float* W2    = (const float*)d_in[10];
    const float* b2    = (const float*)d_in[11];
    const float* W3    = (const float*)d_in[12];
    const float* b3    = (const float*)d_in[13];
    const float* W4    = (const float*)d_in[14];
    const float* b4    = (const float*)d_in[15];
    float* out = (float*)d_out;

    char* ws = (char*)d_ws;
    // ws layout (bytes)
    const size_t o_flag = 0;                       // 4 layers * 2 dirs * 32 wg * 128B = 32 KB
    const size_t o_hbuf = 32768;                   // 2*2*512 f
    const size_t o_zin  = 65536;                   // 2*512*2048 f = 8 MB
    const size_t o_outA = o_zin  + (size_t)2 * SEQ * H4 * 4 + 512;
    const size_t o_outB = o_outA + (size_t)SEQ * H2 * 4 + 512;
    const size_t o_avail= o_outB + (size_t)SEQ * H2 * 4 + 512;
    const size_t o_Abuf = o_avail+ (size_t)MPAD * H2 * 4 + 512;
    const size_t o_Bbuf = o_Abuf + (size_t)MPAD * 256 * 4 + 512;
    const size_t o_W2T  = o_Bbuf + (size_t)MPAD * 256 * 4 + 512;
    const size_t o_W3T  = o_W2T  + 256 * 128 * 4 + 512;
    const size_t o_S    = o_W3T  + 128 * 64 * 4 + 512;
    const size_t o_rl   = o_S    + (size_t)NN * NN * 4 + 512;

    int*   flagb = (int*)  (ws + o_flag);
    float* hbuf  = (float*)(ws + o_hbuf);
    float* zin   = (float*)(ws + o_zin);
    float* outA  = (float*)(ws + o_outA);
    float* outB  = (float*)(ws + o_outB);
    float* avail = (float*)(ws + o_avail);
    float* Abuf  = (float*)(ws + o_Abuf);
    float* Bbuf  = (float*)(ws + o_Bbuf);
    float* W2T   = (float*)(ws + o_W2T);
    float* W3T   = (float*)(ws + o_W3T);
    float* Sbuf  = (float*)(ws + o_S);
    float* rowl  = (float*)(ws + o_rl);

    hipMemsetAsync(ws, 0, 32768, stream);   // per-WG step flags (all layers)

    // layer 0
    gemm_nt<<<dim3(H4 / 64, SEQ / 64, 2), 256, 0, stream>>>(
        x, EMB, 0, Wih0, EMB, (long)H4 * EMB, b0, H4,
        zin, H4, (long)SEQ * H4, EMB);
    lstm_layer<<<64, 256, 0, stream>>>(zin, Whh0, outA, hbuf, flagb + 0 * 2048);

    // layers 1..3
    float* bufs[2] = { outA, outB };
    for (int l = 1; l <= 3; l++) {
        const float* src = bufs[(l - 1) & 1];
        float* dst = bufs[l & 1];
        gemm_nt<<<dim3(H4 / 64, SEQ / 64, 2), 256, 0, stream>>>(
            src, H2, 0, Wih_r + (size_t)(l - 1) * 2 * H4 * H2, H2, (long)H4 * H2,
            b_r + (size_t)(l - 1) * 2 * H4, H4,
            zin, H4, (long)SEQ * H4, H2);
        lstm_layer<<<64, 256, 0, stream>>>(
            zin, Whh_r + (size_t)(l - 1) * 2 * H4 * HID, dst, hbuf, flagb + l * 2048);
    }
    float* lstm_final = bufs[3 & 1];   // outB

    build_avail<<<(MPAD * H2) / 256, 256, 0, stream>>>(lstm_final, avail);

    // A = avail @ W1[:, :1024].T ; B = avail @ W1[:, 1024:].T
    gemm_nt<<<dim3(256 / 64, MPAD / 64, 1), 256, 0, stream>>>(
        avail, H2, 0, W1, 2048, 0, nullptr, 0, Abuf, 256, 0, H2);
    gemm_nt<<<dim3(256 / 64, MPAD / 64, 1), 256, 0, stream>>>(
        avail, H2, 0, W1 + 1024, 2048, 0, nullptr, 0, Bbuf, 256, 0, H2);

    transpose_w<<<(128 * 256) / 256, 256, 0, stream>>>(W2, W2T, 128, 256);
    transpose_w<<<(64 * 128) / 256, 256, 0, stream>>>(W3, W3T, 64, 128);

    pair_kernel<<<dim3(65, 65), 256, 0, stream>>>(
        Abuf, Bbuf, b1, W2T, b2, W3T, b3, W4, b4, Sbuf);

    softmax_row<<<NN, 256, 0, stream>>>(Sbuf, heads, out + 1, rowl);
    finish_loss<<<1, 256, 0, stream>>>(rowl, out);
}

// Round 3
// 5499.328 us; speedup vs baseline: 2.2855x; 2.2855x over previous
//
#include <hip/hip_runtime.h>
#include <math.h>

#define HID 512
#define SEQ 512
#define EMB 345
#define NN  513
#define MPAD 576
#define H4  2048
#define H2  1024

// ---------------------------------------------------------------- GEMM (NT)
// C[m][n] = sum_k A[m][k]*B[n][k] (+ bias[n]); BM=BN=64, TK=16, 256 thr, 4x4
__global__ __launch_bounds__(256)
void gemm_nt(const float* __restrict__ A, int lda, long aStride,
             const float* __restrict__ B, int ldb, long bStride,
             const float* __restrict__ bias, long biasStride,
             float* __restrict__ C, int ldc, long cStride, int K)
{
    int z = blockIdx.z;
    A += (long)z * aStride; B += (long)z * bStride; C += (long)z * cStride;
    const float* bptr = bias ? bias + (long)z * biasStride : nullptr;
    __shared__ float As[16][68];
    __shared__ float Bs[16][68];
    int tid = threadIdx.x;
    int tx = tid & 15, ty = tid >> 4;
    int m0 = blockIdx.y * 64, n0 = blockIdx.x * 64;
    float acc[4][4] = {};
    for (int k0 = 0; k0 < K; k0 += 16) {
        #pragma unroll
        for (int i = 0; i < 4; i++) {
            int id = tid + 256 * i;
            int mn = id >> 4, kk = id & 15;
            int k = k0 + kk;
            As[kk][mn] = (k < K) ? A[(long)(m0 + mn) * lda + k] : 0.f;
            Bs[kk][mn] = (k < K) ? B[(long)(n0 + mn) * ldb + k] : 0.f;
        }
        __syncthreads();
        #pragma unroll
        for (int kk = 0; kk < 16; kk++) {
            float a[4], b[4];
            #pragma unroll
            for (int i = 0; i < 4; i++) a[i] = As[kk][ty * 4 + i];
            #pragma unroll
            for (int j = 0; j < 4; j++) b[j] = Bs[kk][tx * 4 + j];
            #pragma unroll
            for (int i = 0; i < 4; i++)
                #pragma unroll
                for (int j = 0; j < 4; j++) acc[i][j] += a[i] * b[j];
        }
        __syncthreads();
    }
    #pragma unroll
    for (int i = 0; i < 4; i++) {
        int m = m0 + ty * 4 + i;
        #pragma unroll
        for (int j = 0; j < 4; j++) {
            int n = n0 + tx * 4 + j;
            float v = acc[i][j];
            if (bptr) v += bptr[n];
            C[(long)m * ldc + n] = v;
        }
    }
}

// ---------------------------------------------------------------- LSTM layer
__device__ __forceinline__ float sigmf(float x) { return 1.f / (1.f + __expf(-x)); }

// 64 WGs: wg>>5 = dir, (wg&31)*16 = cell base. Weights register-resident.
// NO flags: `out` is pre-filled with 0xFF (-NaN, unreachable for h) and the
// producers' device-scope stores of h into `out` ARE the ready signal.
// Consumers poll the h words of step t-1 directly (wave p polls its own
// 128-float chunk). One round trip on the critical path instead of three.
__global__ __launch_bounds__(256, 1)
void lstm_layer(const float* __restrict__ zin,   // [2][SEQ][H4]
                const float* __restrict__ Whh,   // [2][H4][HID]
                float* out)                      // [SEQ][H2], pre-memset 0xFF
{
    int wg  = blockIdx.x;
    int dir = wg >> 5;
    int kb  = (wg & 31) * 16;
    int tid = threadIdx.x;
    int r = tid & 63;          // row (gate*16 + kq)
    int p = tid >> 6;          // wave id = k-part 0..3
    int gate = r >> 4;
    int kq = r & 15;
    long row = (long)gate * 512 + kb + kq;

    __shared__ float h_lds[512];
    __shared__ float part[256];
    __shared__ float rowsum[64];

    float4 wreg[32];
    const float4* wp = (const float4*)(Whh + ((long)dir * H4 + row) * HID + p * 128);
    #pragma unroll
    for (int j = 0; j < 32; j++) wreg[j] = wp[j];

    const float* zin_d = zin + (long)dir * SEQ * H4;
    float c_st = 0.f;
    int lane = tid & 63;

    for (int t = 0; t < SEQ; t++) {
        int at = (dir == 0) ? t : (SEQ - 1 - t);
        // prefetch zin (independent of the wait)
        float z0 = 0.f, z1 = 0.f, z2 = 0.f, z3 = 0.f;
        if (tid < 16) {
            const float* zp = zin_d + (long)at * H4 + kb + tid;
            z0 = zp[0]; z1 = zp[512]; z2 = zp[1024]; z3 = zp[1536];
        }
        if (t == 0) {
            h_lds[tid] = 0.f; h_lds[tid + 256] = 0.f;
        } else if (lane < 32) {
            int at_prev = (dir == 0) ? (t - 1) : (SEQ - t);
            const unsigned long long* src =
                (const unsigned long long*)(out + (long)at_prev * H2 + dir * HID + p * 128)
                + lane * 2;
            unsigned long long a = __hip_atomic_load(src,     __ATOMIC_RELAXED, __HIP_MEMORY_SCOPE_AGENT);
            unsigned long long b = __hip_atomic_load(src + 1, __ATOMIC_RELAXED, __HIP_MEMORY_SCOPE_AGENT);
            while (((unsigned)a == 0xFFFFFFFFu) | ((unsigned)(a >> 32) == 0xFFFFFFFFu) |
                   ((unsigned)b == 0xFFFFFFFFu) | ((unsigned)(b >> 32) == 0xFFFFFFFFu)) {
                __builtin_amdgcn_s_sleep(1);
                a = __hip_atomic_load(src,     __ATOMIC_RELAXED, __HIP_MEMORY_SCOPE_AGENT);
                b = __hip_atomic_load(src + 1, __ATOMIC_RELAXED, __HIP_MEMORY_SCOPE_AGENT);
            }
            union { unsigned long long u[2]; float4 f; } cv;
            cv.u[0] = a; cv.u[1] = b;
            *(float4*)&h_lds[p * 128 + lane * 4] = cv.f;
        }
        __syncthreads();       // h_lds ready (also separates reuse across steps)
        // MAC: wave p covers k in [p*128, p*128+128); broadcast LDS reads
        const float4* h4 = (const float4*)(h_lds + p * 128);
        float4 av = {0.f, 0.f, 0.f, 0.f};
        #pragma unroll
        for (int j = 0; j < 32; j++) {
            float4 w = wreg[j], h = h4[j];
            av.x += w.x * h.x; av.y += w.y * h.y;
            av.z += w.z * h.z; av.w += w.w * h.w;
        }
        part[tid] = (av.x + av.y) + (av.z + av.w);
        __syncthreads();
        if (tid < 64) rowsum[tid] = part[tid] + part[tid + 64] + part[tid + 128] + part[tid + 192];
        __syncthreads();
        if (tid < 16) {
            float zi = z0 + rowsum[tid];
            float zf = z1 + rowsum[16 + tid];
            float zg = z2 + rowsum[32 + tid];
            float zo = z3 + rowsum[48 + tid];
            float cc = sigmf(zf) * c_st + sigmf(zi) * tanhf(zg);
            c_st = cc;
            float hh = sigmf(zo) * tanhf(cc);
            // single publish: the out-write IS the ready flag for step t
            __hip_atomic_store(out + (long)at * H2 + dir * HID + kb + tid, hh,
                               __ATOMIC_RELAXED, __HIP_MEMORY_SCOPE_AGENT);
        }
    }
}

// ---------------------------------------------------------------- avail build
__global__ __launch_bounds__(256)
void build_avail(const float* __restrict__ lstm_out, float* __restrict__ avail)
{
    long idx = (long)blockIdx.x * 256 + threadIdx.x;   // over MPAD*H2
    if (idx >= (long)MPAD * H2) return;
    int i = (int)(idx >> 10);
    int c = (int)(idx & 1023);
    float v = 0.f;
    if (i >= 1 && i <= SEQ) v = lstm_out[(long)(i - 1) * H2 + c];
    avail[idx] = v;
}

// ---------------------------------------------------------------- transpose
__global__ __launch_bounds__(256)
void transpose_w(const float* __restrict__ W, float* __restrict__ WT, int rows, int cols)
{
    int idx = blockIdx.x * 256 + threadIdx.x;
    if (idx >= rows * cols) return;
    int rr = idx / cols, cc = idx % cols;
    WT[cc * rows + rr] = W[idx];
}

// ---------------------------------------------------------------- pair MLP
#define STR1 257
#define STR2 129
__global__ __launch_bounds__(256)
void pair_kernel(const float* __restrict__ Abuf, const float* __restrict__ Bbuf,
                 const float* __restrict__ b1, const float* __restrict__ W2T,
                 const float* __restrict__ b2, const float* __restrict__ W3T,
                 const float* __restrict__ b3, const float* __restrict__ W4,
                 const float* __restrict__ b4, float* __restrict__ S)
{
    __shared__ float At[8 * STR1];
    __shared__ float Bt[8 * STR1];
    __shared__ float b1s[256];
    __shared__ float h2s[64 * STR2];
    __shared__ float spart[4 * 64];
    int tid = threadIdx.x;
    int i0 = blockIdx.y * 8, j0 = blockIdx.x * 8;
    {
        int rr = tid >> 5;
        int cbase = (tid & 31) * 8;
        #pragma unroll
        for (int u = 0; u < 8; u++) {
            At[rr * STR1 + cbase + u] = Abuf[(long)(i0 + rr) * 256 + cbase + u];
            Bt[rr * STR1 + cbase + u] = Bbuf[(long)(j0 + rr) * 256 + cbase + u];
        }
        b1s[tid] = b1[tid];
    }
    __syncthreads();
    int w = tid >> 6;
    int lane = tid & 63;          // pair id
    int ii = lane >> 3, jj = lane & 7;
    // phase 2: h1 (on the fly) -> h2
    #pragma unroll 1
    for (int blk = 0; blk < 4; blk++) {
        int c2b = __builtin_amdgcn_readfirstlane(w * 32 + blk * 8);
        float acc[8] = {};
        #pragma unroll 4
        for (int c1 = 0; c1 < 256; c1++) {
            float h1v = At[ii * STR1 + c1] + Bt[jj * STR1 + c1] + b1s[c1];
            h1v = fmaxf(h1v, 0.f);
            const float* wrow = W2T + c1 * 128 + c2b;
            #pragma unroll
            for (int u = 0; u < 8; u++) acc[u] += wrow[u] * h1v;
        }
        #pragma unroll
        for (int u = 0; u < 8; u++)
            h2s[lane * STR2 + c2b + u] = fmaxf(acc[u] + b2[c2b + u], 0.f);
    }
    __syncthreads();
    // phase 3: h2 -> h3, W4 fused
    float sp = 0.f;
    #pragma unroll 1
    for (int blk = 0; blk < 2; blk++) {
        int c3b = __builtin_amdgcn_readfirstlane(w * 16 + blk * 8);
        float acc[8] = {};
        #pragma unroll 4
        for (int c2 = 0; c2 < 128; c2++) {
            float h2v = h2s[lane * STR2 + c2];
            const float* wrow = W3T + c2 * 64 + c3b;
            #pragma unroll
            for (int u = 0; u < 8; u++) acc[u] += wrow[u] * h2v;
        }
        #pragma unroll
        for (int u = 0; u < 8; u++) {
            float v = fmaxf(acc[u] + b3[c3b + u], 0.f);
            sp += W4[c3b + u] * v;
        }
    }
    spart[w * 64 + lane] = sp;
    __syncthreads();
    if (tid < 64) {
        float s = spart[tid] + spart[64 + tid] + spart[128 + tid] + spart[192 + tid] + b4[0];
        int i = i0 + (tid >> 3), j = j0 + (tid & 7);
        if (i < NN && j < NN) S[(long)i * NN + j] = s;
    }
}

// ---------------------------------------------------------------- softmax+loss
__global__ __launch_bounds__(256)
void softmax_row(const float* __restrict__ S, const int* __restrict__ heads,
                 float* __restrict__ probs, float* __restrict__ rowloss)
{
    int i = blockIdx.x;
    int tid = threadIdx.x;
    __shared__ float red[256];
    __shared__ float srow[NN];
    const float* Si = S + (long)i * NN;
    float mx = -1e30f;
    for (int j = tid; j < NN; j += 256) { float v = Si[j]; srow[j] = v; mx = fmaxf(mx, v); }
    red[tid] = mx; __syncthreads();
    for (int s = 128; s > 0; s >>= 1) { if (tid < s) red[tid] = fmaxf(red[tid], red[tid + s]); __syncthreads(); }
    mx = red[0]; __syncthreads();
    float sum = 0.f, sq = 0.f;
    int hd = heads[i];
    for (int j = tid; j < NN; j += 256) {
        float v = srow[j];
        sum += __expf(v - mx);
        float t = (j == hd) ? 100.f : 0.f;
        float d = v - t; sq += d * d;
    }
    red[tid] = sum; __syncthreads();
    for (int s = 128; s > 0; s >>= 1) { if (tid < s) red[tid] += red[tid + s]; __syncthreads(); }
    sum = red[0]; __syncthreads();
    red[tid] = sq; __syncthreads();
    for (int s = 128; s > 0; s >>= 1) { if (tid < s) red[tid] += red[tid + s]; __syncthreads(); }
    if (tid == 0) rowloss[i] = red[0];
    float inv = 1.f / sum;
    for (int j = tid; j < NN; j += 256) probs[(long)i * NN + j] = __expf(srow[j] - mx) * inv;
}

__global__ __launch_bounds__(256)
void finish_loss(const float* __restrict__ rowloss, float* __restrict__ out0)
{
    __shared__ float red[256];
    int tid = threadIdx.x;
    float s = 0.f;
    for (int i = tid; i < NN; i += 256) s += rowloss[i];
    red[tid] = s; __syncthreads();
    for (int k = 128; k > 0; k >>= 1) { if (tid < k) red[tid] += red[tid + k]; __syncthreads(); }
    if (tid == 0) out0[0] = red[0] / ((float)NN * (float)NN);
}

// ---------------------------------------------------------------- launch
extern "C" void kernel_launch(void* const* d_in, const int* in_sizes, int n_in,
                              void* d_out, int out_size, void* d_ws, size_t ws_size,
                              hipStream_t stream)
{
    const float* x     = (const float*)d_in[0];
    const int*   heads = (const int*)  d_in[1];
    const float* Wih0  = (const float*)d_in[2];
    const float* Whh0  = (const float*)d_in[3];
    const float* b0    = (const float*)d_in[4];
    const float* Wih_r = (const float*)d_in[5];
    const float* Whh_r = (const float*)d_in[6];
    const float* b_r   = (const float*)d_in[7];
    const float* W1    = (const float*)d_in[8];
    const float* b1    = (const float*)d_in[9];
    const float* W2    = (const float*)d_in[10];
    const float* b2    = (const float*)d_in[11];
    const float* W3    = (const float*)d_in[12];
    const float* b3    = (const float*)d_in[13];
    const float* W4    = (const float*)d_in[14];
    const float* b4    = (const float*)d_in[15];
    float* out = (float*)d_out;

    char* ws = (char*)d_ws;
    // ws layout (bytes)
    const size_t o_zin  = 0;                       // 2*512*2048 f = 8 MB
    const size_t o_outA = o_zin  + (size_t)2 * SEQ * H4 * 4 + 512;
    const size_t o_outB = o_outA + (size_t)SEQ * H2 * 4 + 512;
    const size_t o_avail= o_outB + (size_t)SEQ * H2 * 4 + 512;
    const size_t o_Abuf = o_avail+ (size_t)MPAD * H2 * 4 + 512;
    const size_t o_Bbuf = o_Abuf + (size_t)MPAD * 256 * 4 + 512;
    const size_t o_W2T  = o_Bbuf + (size_t)MPAD * 256 * 4 + 512;
    const size_t o_W3T  = o_W2T  + 256 * 128 * 4 + 512;
    const size_t o_S    = o_W3T  + 128 * 64 * 4 + 512;
    const size_t o_rl   = o_S    + (size_t)NN * NN * 4 + 512;

    float* zin   = (float*)(ws + o_zin);
    float* outA  = (float*)(ws + o_outA);
    float* outB  = (float*)(ws + o_outB);
    float* avail = (float*)(ws + o_avail);
    float* Abuf  = (float*)(ws + o_Abuf);
    float* Bbuf  = (float*)(ws + o_Bbuf);
    float* W2T   = (float*)(ws + o_W2T);
    float* W3T   = (float*)(ws + o_W3T);
    float* Sbuf  = (float*)(ws + o_S);
    float* rowl  = (float*)(ws + o_rl);

    const size_t outBytes = (size_t)SEQ * H2 * 4;   // 2 MB

    // layer 0
    gemm_nt<<<dim3(H4 / 64, SEQ / 64, 2), 256, 0, stream>>>(
        x, EMB, 0, Wih0, EMB, (long)H4 * EMB, b0, H4,
        zin, H4, (long)SEQ * H4, EMB);
    hipMemsetAsync(outA, 0xFF, outBytes, stream);   // sentinel fill for poll
    lstm_layer<<<64, 256, 0, stream>>>(zin, Whh0, outA);

    // layers 1..3 (dst pre-filled 0xFF after its last reader finished)
    float* bufs[2] = { outA, outB };
    for (int l = 1; l <= 3; l++) {
        const float* src = bufs[(l - 1) & 1];
        float* dst = bufs[l & 1];
        gemm_nt<<<dim3(H4 / 64, SEQ / 64, 2), 256, 0, stream>>>(
            src, H2, 0, Wih_r + (size_t)(l - 1) * 2 * H4 * H2, H2, (long)H4 * H2,
            b_r + (size_t)(l - 1) * 2 * H4, H4,
            zin, H4, (long)SEQ * H4, H2);
        hipMemsetAsync(dst, 0xFF, outBytes, stream);
        lstm_layer<<<64, 256, 0, stream>>>(
            zin, Whh_r + (size_t)(l - 1) * 2 * H4 * HID, dst);
    }
    float* lstm_final = bufs[3 & 1];   // outB

    build_avail<<<(MPAD * H2) / 256, 256, 0, stream>>>(lstm_final, avail);

    // A = avail @ W1[:, :1024].T ; B = avail @ W1[:, 1024:].T
    gemm_nt<<<dim3(256 / 64, MPAD / 64, 1), 256, 0, stream>>>(
        avail, H2, 0, W1, 2048, 0, nullptr, 0, Abuf, 256, 0, H2);
    gemm_nt<<<dim3(256 / 64, MPAD / 64, 1), 256, 0, stream>>>(
        avail, H2, 0, W1 + 1024, 2048, 0, nullptr, 0, Bbuf, 256, 0, H2);

    transpose_w<<<(128 * 256) / 256, 256, 0, stream>>>(W2, W2T, 128, 256);
    transpose_w<<<(64 * 128) / 256, 256, 0, stream>>>(W3, W3T, 64, 128);

    pair_kernel<<<dim3(65, 65), 256, 0, stream>>>(
        Abuf, Bbuf, b1, W2T, b2, W3T, b3, W4, b4, Sbuf);

    softmax_row<<<NN, 256, 0, stream>>>(Sbuf, heads, out + 1, rowl);
    finish_loss<<<1, 256, 0, stream>>>(rowl, out);
}

// Round 4
// 4804.749 us; speedup vs baseline: 2.6159x; 1.1446x over previous
//
#include <hip/hip_runtime.h>
#include <math.h>

#define HID 512
#define SEQ 512
#define EMB 345
#define NN  513
#define MPAD 576
#define H4  2048
#define H2  1024

// ---------------------------------------------------------------- GEMM (NT)
// C[m][n] = sum_k A[m][k]*B[n][k] (+ bias[n]); BM=BN=64, TK=16, 256 thr, 4x4
__global__ __launch_bounds__(256)
void gemm_nt(const float* __restrict__ A, int lda, long aStride,
             const float* __restrict__ B, int ldb, long bStride,
             const float* __restrict__ bias, long biasStride,
             float* __restrict__ C, int ldc, long cStride, int K)
{
    int z = blockIdx.z;
    A += (long)z * aStride; B += (long)z * bStride; C += (long)z * cStride;
    const float* bptr = bias ? bias + (long)z * biasStride : nullptr;
    __shared__ float As[16][68];
    __shared__ float Bs[16][68];
    int tid = threadIdx.x;
    int tx = tid & 15, ty = tid >> 4;
    int m0 = blockIdx.y * 64, n0 = blockIdx.x * 64;
    float acc[4][4] = {};
    for (int k0 = 0; k0 < K; k0 += 16) {
        #pragma unroll
        for (int i = 0; i < 4; i++) {
            int id = tid + 256 * i;
            int mn = id >> 4, kk = id & 15;
            int k = k0 + kk;
            As[kk][mn] = (k < K) ? A[(long)(m0 + mn) * lda + k] : 0.f;
            Bs[kk][mn] = (k < K) ? B[(long)(n0 + mn) * ldb + k] : 0.f;
        }
        __syncthreads();
        #pragma unroll
        for (int kk = 0; kk < 16; kk++) {
            float a[4], b[4];
            #pragma unroll
            for (int i = 0; i < 4; i++) a[i] = As[kk][ty * 4 + i];
            #pragma unroll
            for (int j = 0; j < 4; j++) b[j] = Bs[kk][tx * 4 + j];
            #pragma unroll
            for (int i = 0; i < 4; i++)
                #pragma unroll
                for (int j = 0; j < 4; j++) acc[i][j] += a[i] * b[j];
        }
        __syncthreads();
    }
    #pragma unroll
    for (int i = 0; i < 4; i++) {
        int m = m0 + ty * 4 + i;
        #pragma unroll
        for (int j = 0; j < 4; j++) {
            int n = n0 + tx * 4 + j;
            float v = acc[i][j];
            if (bptr) v += bptr[n];
            C[(long)m * ldc + n] = v;
        }
    }
}

// ---------------------------------------------------------------- LSTM layer
// fast activations: v_exp_f32 + v_rcp_f32 (~1e-6 rel err; tolerance is 0.39)
__device__ __forceinline__ float sigmf(float x)
{ return __builtin_amdgcn_rcpf(1.f + __expf(-x)); }
__device__ __forceinline__ float tanhf_fast(float x)
{ return 1.f - 2.f * __builtin_amdgcn_rcpf(1.f + __expf(2.f * x)); }
// x=+inf: exp=inf, rcp=0 -> 1; x=-inf: exp=0 -> -1. No NaN.

// 64 WGs: wg>>5 = dir, (wg&31)*16 = cell base. Weights register-resident.
// Data-as-flag: `out` pre-filled 0xFF (-NaN, unreachable for h in (-1,1));
// producers' agent-scope h stores into `out` ARE the ready signal.
// ONE barrier per step: wave p polls+fills+MACs its private chunk p (no
// inter-wave dependency); part[] is double-buffered so waves 1-3 fall
// through the barrier straight into the next step's poll; wave 0 reduces
// via 4 LDS reads + 3 shuffles and runs the activation chain.
__global__ __launch_bounds__(256, 1)
void lstm_layer(const float* __restrict__ zin,   // [2][SEQ][H4]
                const float* __restrict__ Whh,   // [2][H4][HID]
                float* out)                      // [SEQ][H2], pre-memset 0xFF
{
    int wg  = blockIdx.x;
    int dir = wg >> 5;
    int kb  = (wg & 31) * 16;
    int tid = threadIdx.x;
    int lane = tid & 63;
    int p = tid >> 6;          // wave id = k-chunk 0..3
    int gate = lane >> 4;
    int kq = lane & 15;
    long row = (long)gate * 512 + kb + kq;

    __shared__ float h_lds[512];
    __shared__ float part[2][256];

    float4 wreg[32];
    const float4* wp = (const float4*)(Whh + ((long)dir * H4 + row) * HID + p * 128);
    #pragma unroll
    for (int j = 0; j < 32; j++) wreg[j] = wp[j];

    const float* zin_d = zin + (long)dir * SEQ * H4;
    float c_st = 0.f;

    // zero own chunk (wave-local; intra-wave lgkmcnt orders vs first MAC)
    h_lds[p * 128 + lane] = 0.f;
    h_lds[p * 128 + 64 + lane] = 0.f;

    for (int t = 0; t < SEQ; t++) {
        int at = (dir == 0) ? t : (SEQ - 1 - t);
        // wave-0 prefetch of zin (issued before the poll, hidden behind it)
        float z0 = 0.f, z1 = 0.f, z2 = 0.f, z3 = 0.f;
        if (tid < 16) {
            const float* zp = zin_d + (long)at * H4 + kb + tid;
            z0 = zp[0]; z1 = zp[512]; z2 = zp[1024]; z3 = zp[1536];
        }
        if (t > 0) {
            int at_prev = (dir == 0) ? (t - 1) : (SEQ - t);
            const unsigned long long* src =
                (const unsigned long long*)(out + (long)at_prev * H2 + dir * HID + p * 128)
                + lane;
            unsigned long long a = __hip_atomic_load(src, __ATOMIC_RELAXED, __HIP_MEMORY_SCOPE_AGENT);
            while (((unsigned)a == 0xFFFFFFFFu) | ((unsigned)(a >> 32) == 0xFFFFFFFFu)) {
                __builtin_amdgcn_s_sleep(1);
                a = __hip_atomic_load(src, __ATOMIC_RELAXED, __HIP_MEMORY_SCOPE_AGENT);
            }
            union { unsigned long long u; float2 f; } cv;
            cv.u = a;
            *(float2*)&h_lds[p * 128 + lane * 2] = cv.f;
        }
        // MAC over own chunk (broadcast LDS reads; no barrier needed: chunk
        // p is written and read only by wave p, ordered by lgkmcnt)
        const float4* h4 = (const float4*)(h_lds + p * 128);
        float4 av = {0.f, 0.f, 0.f, 0.f};
        #pragma unroll
        for (int j = 0; j < 32; j++) {
            float4 w = wreg[j], h = h4[j];
            av.x += w.x * h.x; av.y += w.y * h.y;
            av.z += w.z * h.z; av.w += w.w * h.w;
        }
        part[t & 1][tid] = (av.x + av.y) + (av.z + av.w);
        __syncthreads();       // the ONLY barrier per step
        if (p == 0) {
            const float* pb = part[t & 1];
            float rs = pb[lane] + pb[lane + 64] + pb[lane + 128] + pb[lane + 192];
            // rows: lane<16 needs r=lane(i), +16(f), +32(g), +48(o)
            float rf = __shfl(rs, (lane & 15) + 16);
            float rg = __shfl(rs, (lane & 15) + 32);
            float ro = __shfl(rs, (lane & 15) + 48);
            if (lane < 16) {
                float zi = z0 + rs;
                float zf = z1 + rf;
                float zg = z2 + rg;
                float zo = z3 + ro;
                float cc = sigmf(zf) * c_st + sigmf(zi) * tanhf_fast(zg);
                c_st = cc;
                float hh = sigmf(zo) * tanhf_fast(cc);
                // single publish: the out-write IS the ready flag
                __hip_atomic_store(out + (long)at * H2 + dir * HID + kb + lane, hh,
                                   __ATOMIC_RELAXED, __HIP_MEMORY_SCOPE_AGENT);
            }
        }
    }
}

// ---------------------------------------------------------------- avail build
__global__ __launch_bounds__(256)
void build_avail(const float* __restrict__ lstm_out, float* __restrict__ avail)
{
    long idx = (long)blockIdx.x * 256 + threadIdx.x;   // over MPAD*H2
    if (idx >= (long)MPAD * H2) return;
    int i = (int)(idx >> 10);
    int c = (int)(idx & 1023);
    float v = 0.f;
    if (i >= 1 && i <= SEQ) v = lstm_out[(long)(i - 1) * H2 + c];
    avail[idx] = v;
}

// ---------------------------------------------------------------- transpose
__global__ __launch_bounds__(256)
void transpose_w(const float* __restrict__ W, float* __restrict__ WT, int rows, int cols)
{
    int idx = blockIdx.x * 256 + threadIdx.x;
    if (idx >= rows * cols) return;
    int rr = idx / cols, cc = idx % cols;
    WT[cc * rows + rr] = W[idx];
}

// ---------------------------------------------------------------- pair MLP
#define STR1 257
#define STR2 129
__global__ __launch_bounds__(256)
void pair_kernel(const float* __restrict__ Abuf, const float* __restrict__ Bbuf,
                 const float* __restrict__ b1, const float* __restrict__ W2T,
                 const float* __restrict__ b2, const float* __restrict__ W3T,
                 const float* __restrict__ b3, const float* __restrict__ W4,
                 const float* __restrict__ b4, float* __restrict__ S)
{
    __shared__ float At[8 * STR1];
    __shared__ float Bt[8 * STR1];
    __shared__ float b1s[256];
    __shared__ float h2s[64 * STR2];
    __shared__ float spart[4 * 64];
    int tid = threadIdx.x;
    int i0 = blockIdx.y * 8, j0 = blockIdx.x * 8;
    {
        int rr = tid >> 5;
        int cbase = (tid & 31) * 8;
        #pragma unroll
        for (int u = 0; u < 8; u++) {
            At[rr * STR1 + cbase + u] = Abuf[(long)(i0 + rr) * 256 + cbase + u];
            Bt[rr * STR1 + cbase + u] = Bbuf[(long)(j0 + rr) * 256 + cbase + u];
        }
        b1s[tid] = b1[tid];
    }
    __syncthreads();
    int w = tid >> 6;
    int lane = tid & 63;          // pair id
    int ii = lane >> 3, jj = lane & 7;
    // phase 2: h1 (on the fly) -> h2
    #pragma unroll 1
    for (int blk = 0; blk < 4; blk++) {
        int c2b = __builtin_amdgcn_readfirstlane(w * 32 + blk * 8);
        float acc[8] = {};
        #pragma unroll 4
        for (int c1 = 0; c1 < 256; c1++) {
            float h1v = At[ii * STR1 + c1] + Bt[jj * STR1 + c1] + b1s[c1];
            h1v = fmaxf(h1v, 0.f);
            const float* wrow = W2T + c1 * 128 + c2b;
            #pragma unroll
            for (int u = 0; u < 8; u++) acc[u] += wrow[u] * h1v;
        }
        #pragma unroll
        for (int u = 0; u < 8; u++)
            h2s[lane * STR2 + c2b + u] = fmaxf(acc[u] + b2[c2b + u], 0.f);
    }
    __syncthreads();
    // phase 3: h2 -> h3, W4 fused
    float sp = 0.f;
    #pragma unroll 1
    for (int blk = 0; blk < 2; blk++) {
        int c3b = __builtin_amdgcn_readfirstlane(w * 16 + blk * 8);
        float acc[8] = {};
        #pragma unroll 4
        for (int c2 = 0; c2 < 128; c2++) {
            float h2v = h2s[lane * STR2 + c2];
            const float* wrow = W3T + c2 * 64 + c3b;
            #pragma unroll
            for (int u = 0; u < 8; u++) acc[u] += wrow[u] * h2v;
        }
        #pragma unroll
        for (int u = 0; u < 8; u++) {
            float v = fmaxf(acc[u] + b3[c3b + u], 0.f);
            sp += W4[c3b + u] * v;
        }
    }
    spart[w * 64 + lane] = sp;
    __syncthreads();
    if (tid < 64) {
        float s = spart[tid] + spart[64 + tid] + spart[128 + tid] + spart[192 + tid] + b4[0];
        int i = i0 + (tid >> 3), j = j0 + (tid & 7);
        if (i < NN && j < NN) S[(long)i * NN + j] = s;
    }
}

// ---------------------------------------------------------------- softmax+loss
__global__ __launch_bounds__(256)
void softmax_row(const float* __restrict__ S, const int* __restrict__ heads,
                 float* __restrict__ probs, float* __restrict__ rowloss)
{
    int i = blockIdx.x;
    int tid = threadIdx.x;
    __shared__ float red[256];
    __shared__ float srow[NN];
    const float* Si = S + (long)i * NN;
    float mx = -1e30f;
    for (int j = tid; j < NN; j += 256) { float v = Si[j]; srow[j] = v; mx = fmaxf(mx, v); }
    red[tid] = mx; __syncthreads();
    for (int s = 128; s > 0; s >>= 1) { if (tid < s) red[tid] = fmaxf(red[tid], red[tid + s]); __syncthreads(); }
    mx = red[0]; __syncthreads();
    float sum = 0.f, sq = 0.f;
    int hd = heads[i];
    for (int j = tid; j < NN; j += 256) {
        float v = srow[j];
        sum += __expf(v - mx);
        float t = (j == hd) ? 100.f : 0.f;
        float d = v - t; sq += d * d;
    }
    red[tid] = sum; __syncthreads();
    for (int s = 128; s > 0; s >>= 1) { if (tid < s) red[tid] += red[tid + s]; __syncthreads(); }
    sum = red[0]; __syncthreads();
    red[tid] = sq; __syncthreads();
    for (int s = 128; s > 0; s >>= 1) { if (tid < s) red[tid] += red[tid + s]; __syncthreads(); }
    if (tid == 0) rowloss[i] = red[0];
    float inv = 1.f / sum;
    for (int j = tid; j < NN; j += 256) probs[(long)i * NN + j] = __expf(srow[j] - mx) * inv;
}

__global__ __launch_bounds__(256)
void finish_loss(const float* __restrict__ rowloss, float* __restrict__ out0)
{
    __shared__ float red[256];
    int tid = threadIdx.x;
    float s = 0.f;
    for (int i = tid; i < NN; i += 256) s += rowloss[i];
    red[tid] = s; __syncthreads();
    for (int k = 128; k > 0; k >>= 1) { if (tid < k) red[tid] += red[tid + k]; __syncthreads(); }
    if (tid == 0) out0[0] = red[0] / ((float)NN * (float)NN);
}

// ---------------------------------------------------------------- launch
extern "C" void kernel_launch(void* const* d_in, const int* in_sizes, int n_in,
                              void* d_out, int out_size, void* d_ws, size_t ws_size,
                              hipStream_t stream)
{
    const float* x     = (const float*)d_in[0];
    const int*   heads = (const int*)  d_in[1];
    const float* Wih0  = (const float*)d_in[2];
    const float* Whh0  = (const float*)d_in[3];
    const float* b0    = (const float*)d_in[4];
    const float* Wih_r = (const float*)d_in[5];
    const float* Whh_r = (const float*)d_in[6];
    const float* b_r   = (const float*)d_in[7];
    const float* W1    = (const float*)d_in[8];
    const float* b1    = (const float*)d_in[9];
    const float* W2    = (const float*)d_in[10];
    const float* b2    = (const float*)d_in[11];
    const float* W3    = (const float*)d_in[12];
    const float* b3    = (const float*)d_in[13];
    const float* W4    = (const float*)d_in[14];
    const float* b4    = (const float*)d_in[15];
    float* out = (float*)d_out;

    char* ws = (char*)d_ws;
    // ws layout (bytes)
    const size_t o_zin  = 0;                       // 2*512*2048 f = 8 MB
    const size_t o_outA = o_zin  + (size_t)2 * SEQ * H4 * 4 + 512;
    const size_t o_outB = o_outA + (size_t)SEQ * H2 * 4 + 512;
    const size_t o_avail= o_outB + (size_t)SEQ * H2 * 4 + 512;
    const size_t o_Abuf = o_avail+ (size_t)MPAD * H2 * 4 + 512;
    const size_t o_Bbuf = o_Abuf + (size_t)MPAD * 256 * 4 + 512;
    const size_t o_W2T  = o_Bbuf + (size_t)MPAD * 256 * 4 + 512;
    const size_t o_W3T  = o_W2T  + 256 * 128 * 4 + 512;
    const size_t o_S    = o_W3T  + 128 * 64 * 4 + 512;
    const size_t o_rl   = o_S    + (size_t)NN * NN * 4 + 512;

    float* zin   = (float*)(ws + o_zin);
    float* outA  = (float*)(ws + o_outA);
    float* outB  = (float*)(ws + o_outB);
    float* avail = (float*)(ws + o_avail);
    float* Abuf  = (float*)(ws + o_Abuf);
    float* Bbuf  = (float*)(ws + o_Bbuf);
    float* W2T   = (float*)(ws + o_W2T);
    float* W3T   = (float*)(ws + o_W3T);
    float* Sbuf  = (float*)(ws + o_S);
    float* rowl  = (float*)(ws + o_rl);

    const size_t outBytes = (size_t)SEQ * H2 * 4;   // 2 MB

    // layer 0
    gemm_nt<<<dim3(H4 / 64, SEQ / 64, 2), 256, 0, stream>>>(
        x, EMB, 0, Wih0, EMB, (long)H4 * EMB, b0, H4,
        zin, H4, (long)SEQ * H4, EMB);
    hipMemsetAsync(outA, 0xFF, outBytes, stream);   // sentinel fill for poll
    lstm_layer<<<64, 256, 0, stream>>>(zin, Whh0, outA);

    // layers 1..3 (dst pre-filled 0xFF after its last reader finished)
    float* bufs[2] = { outA, outB };
    for (int l = 1; l <= 3; l++) {
        const float* src = bufs[(l - 1) & 1];
        float* dst = bufs[l & 1];
        gemm_nt<<<dim3(H4 / 64, SEQ / 64, 2), 256, 0, stream>>>(
            src, H2, 0, Wih_r + (size_t)(l - 1) * 2 * H4 * H2, H2, (long)H4 * H2,
            b_r + (size_t)(l - 1) * 2 * H4, H4,
            zin, H4, (long)SEQ * H4, H2);
        hipMemsetAsync(dst, 0xFF, outBytes, stream);
        lstm_layer<<<64, 256, 0, stream>>>(
            zin, Whh_r + (size_t)(l - 1) * 2 * H4 * HID, dst);
    }
    float* lstm_final = bufs[3 & 1];   // outB

    build_avail<<<(MPAD * H2) / 256, 256, 0, stream>>>(lstm_final, avail);

    // A = avail @ W1[:, :1024].T ; B = avail @ W1[:, 1024:].T
    gemm_nt<<<dim3(256 / 64, MPAD / 64, 1), 256, 0, stream>>>(
        avail, H2, 0, W1, 2048, 0, nullptr, 0, Abuf, 256, 0, H2);
    gemm_nt<<<dim3(256 / 64, MPAD / 64, 1), 256, 0, stream>>>(
        avail, H2, 0, W1 + 1024, 2048, 0, nullptr, 0, Bbuf, 256, 0, H2);

    transpose_w<<<(128 * 256) / 256, 256, 0, stream>>>(W2, W2T, 128, 256);
    transpose_w<<<(64 * 128) / 256, 256, 0, stream>>>(W3, W3T, 64, 128);

    pair_kernel<<<dim3(65, 65), 256, 0, stream>>>(
        Abuf, Bbuf, b1, W2T, b2, W3T, b3, W4, b4, Sbuf);

    softmax_row<<<NN, 256, 0, stream>>>(Sbuf, heads, out + 1, rowl);
    finish_loss<<<1, 256, 0, stream>>>(rowl, out);
}